// Round 1
// baseline (148.217 us; speedup 1.0000x reference)
//
#include <hip/hip_runtime.h>

// HEALPixPad: x (B=2, 12, C=32, 256, 256) f32 -> (B, 12, C, 260, 260) f32, P=2.
// Pure gather. One thread per output pixel; mapping derived from the JAX ref.

constexpr int N  = 256;
constexpr int P  = 2;
constexpr int NP = N + 2 * P;       // 260
constexpr int C  = 32;
constexpr int PLANE_OUT = NP * NP;  // 67600
constexpr int PLANE_IN  = N * N;    // 65536

__global__ __launch_bounds__(256)
void healpix_pad_kernel(const float* __restrict__ in, float* __restrict__ out, int total) {
    int id = blockIdx.x * blockDim.x + threadIdx.x;
    if (id >= total) return;

    int plane = id / PLANE_OUT;                // (b*12 + face)*C + c
    int pix   = id - plane * PLANE_OUT;
    int oh    = pix / NP;
    int ow    = pix - oh * NP;
    int bc    = plane / C;                     // b*12 + face
    int face  = bc - (bc / 12) * 12;           // face index 0..11
    int i     = face & 3;

    // basePlane + f*C == (b*12 + f)*C + c
    const int basePlane = plane - face * C;

    auto L = [&](int f, int sh, int sw) -> float {
        return in[(size_t)(basePlane + f * C) * PLANE_IN + sh * N + sw];
    };

    float v;

    if (face < 4) {
        // ---- northern polar cap ----
        if (oh < P) {
            if (ow < P) {
                v = L((i + 2) & 3, P - 1 - oh, P - 1 - ow);                 // TL rot180
            } else if (ow < P + N) {
                v = L((i + 1) & 3, ow - P, P - 1 - oh);                     // T rot90
            } else {
                v = L((i + 1) & 3, ow - P - N, P - 1 - oh);                 // TR rot90
            }
        } else if (oh < P + N) {
            int ch = oh - P;
            if (ow < P) {
                v = L((i + 3) & 3, P - 1 - ow, ch);                         // L rot-90
            } else if (ow < P + N) {
                v = L(face, ch, ow - P);                                    // C
            } else {
                v = L(4 + ((i + 1) & 3), ch, ow - P - N);                   // R
            }
        } else {
            int bh = oh - P - N;
            if (ow < P) {
                v = L((i + 3) & 3, bh, N - P + ow);                         // BL
            } else if (ow < P + N) {
                v = L(4 + i, bh, ow - P);                                   // B
            } else {
                v = L(8 + i, bh, ow - P - N);                               // BR
            }
        }
    } else if (face < 8) {
        // ---- equatorial belt ----
        if (oh < P) {
            if (ow < P) {
                // degenerate TL corner: t=f[i], l=f[(i-1)%4]
                if (oh == P - 1 && ow == P - 1)
                    v = 0.5f * L(i, N - 1, 0) + 0.5f * L((i + 3) & 3, 0, N - 1);
                else if (oh == P - 1)
                    v = L((i + 3) & 3, 0, N - P + ow);
                else if (ow == P - 1)
                    v = L(i, N - P + oh, 0);
                else
                    v = 0.0f;
            } else if (ow < P + N) {
                v = L(i, N - P + oh, ow - P);                               // T
            } else {
                v = L(i, N - P + oh, ow - P - N);                           // TR (first P cols of t)
            }
        } else if (oh < P + N) {
            int ch = oh - P;
            if (ow < P) {
                v = L((i + 3) & 3, ch, N - P + ow);                         // L
            } else if (ow < P + N) {
                v = L(face, ch, ow - P);                                    // C
            } else {
                v = L(4 + ((i + 1) & 3), ch, ow - P - N);                   // R
            }
        } else {
            int bh = oh - P - N;
            if (ow < P) {
                v = L(4 + ((i + 3) & 3), bh, N - P + ow);                   // BL
            } else if (ow < P + N) {
                v = L(8 + i, bh, ow - P);                                   // B
            } else {
                int bw = ow - P - N;
                // degenerate BR corner: b=f[8+i], r=f[8+(i-1)%4]
                if (bh == 0 && bw == 0)
                    v = 0.5f * L(8 + i, 0, N - 1) + 0.5f * L(8 + ((i + 3) & 3), N - 1, 0);
                else if (bh == 0)
                    v = L(8 + ((i + 3) & 3), N - 1, bw);
                else if (bw == 0)
                    v = L(8 + i, bh, N - 1);
                else
                    v = 0.0f;
            }
        }
    } else {
        // ---- southern polar cap ----
        if (oh < P) {
            if (ow < P) {
                v = L(4 + i, N - P + oh, ow);                               // TL
            } else if (ow < P + N) {
                v = L(4 + i, N - P + oh, ow - P);                           // T
            } else {
                v = L(i, N - P + oh, N - P + (ow - P - N));                 // TR
            }
        } else if (oh < P + N) {
            int ch = oh - P;
            if (ow < P) {
                v = L(4 + ((i + 1) & 3), ch, N - P + ow);                   // L
            } else if (ow < P + N) {
                v = L(face, ch, ow - P);                                    // C
            } else {
                int bw = ow - P - N;
                v = L(8 + ((i + 1) & 3), N - 1 - bw, ch);                   // R rot-90
            }
        } else {
            int bh = oh - P - N;
            if (ow < P) {
                v = L(8 + ((i + 1) & 3), N - P + ow, N - 1 - bh);           // BL rot90
            } else if (ow < P + N) {
                int cw = ow - P;
                v = L(8 + ((i + 3) & 3), cw, N - 1 - bh);                   // B rot90
            } else {
                int bw = ow - P - N;
                v = L(8 + ((i + 3) & 3), N - 1 - bh, N - 1 - bw);           // BR rot180
            }
        }
    }

    out[(size_t)id] = v;
}

extern "C" void kernel_launch(void* const* d_in, const int* in_sizes, int n_in,
                              void* d_out, int out_size, void* d_ws, size_t ws_size,
                              hipStream_t stream) {
    const float* in = (const float*)d_in[0];
    float* out = (float*)d_out;
    int total = out_size;  // 2*12*32*260*260
    int threads = 256;
    int blocks = (total + threads - 1) / threads;
    healpix_pad_kernel<<<blocks, threads, 0, stream>>>(in, out, total);
}

// Round 2
// 94.904 us; speedup vs baseline: 1.5618x; 1.5618x over previous
//
#include <hip/hip_runtime.h>

// HEALPixPad: x (B=2, 12, C=32, 256, 256) f32 -> (B, 12, C, 260, 260) f32, P=2.
// Vectorized: one thread per aligned output float4 (65 per 260-wide row).
// Interior rows use float2 input loads; halo columns/rows use the scalar
// gather validated in round 1 (absmax 0.0).

constexpr int N  = 256;
constexpr int P  = 2;
constexpr int NP = N + 2 * P;       // 260
constexpr int C  = 32;
constexpr int PLANE_OUT = NP * NP;  // 67600
constexpr int PLANE_IN  = N * N;    // 65536
constexpr int ROW4      = NP / 4;   // 65 float4 per output row
constexpr int PLANE4    = NP * ROW4; // 16900 float4 per plane

// Per-element gather with the full HEALPix neighbor mapping (round-1 verified).
__device__ __forceinline__ float gather(const float* __restrict__ in,
                                        int basePlane, int face, int i,
                                        int oh, int ow) {
    auto L = [&](int f, int sh, int sw) -> float {
        return in[(size_t)(basePlane + f * C) * PLANE_IN + sh * N + sw];
    };

    float v;
    if (face < 4) {
        // ---- northern polar cap ----
        if (oh < P) {
            if (ow < P)              v = L((i + 2) & 3, P - 1 - oh, P - 1 - ow);
            else if (ow < P + N)     v = L((i + 1) & 3, ow - P, P - 1 - oh);
            else                     v = L((i + 1) & 3, ow - P - N, P - 1 - oh);
        } else if (oh < P + N) {
            int ch = oh - P;
            if (ow < P)              v = L((i + 3) & 3, P - 1 - ow, ch);
            else if (ow < P + N)     v = L(face, ch, ow - P);
            else                     v = L(4 + ((i + 1) & 3), ch, ow - P - N);
        } else {
            int bh = oh - P - N;
            if (ow < P)              v = L((i + 3) & 3, bh, N - P + ow);
            else if (ow < P + N)     v = L(4 + i, bh, ow - P);
            else                     v = L(8 + i, bh, ow - P - N);
        }
    } else if (face < 8) {
        // ---- equatorial belt ----
        if (oh < P) {
            if (ow < P) {
                if (oh == P - 1 && ow == P - 1)
                    v = 0.5f * L(i, N - 1, 0) + 0.5f * L((i + 3) & 3, 0, N - 1);
                else if (oh == P - 1) v = L((i + 3) & 3, 0, N - P + ow);
                else if (ow == P - 1) v = L(i, N - P + oh, 0);
                else                  v = 0.0f;
            }
            else if (ow < P + N)     v = L(i, N - P + oh, ow - P);
            else                     v = L(i, N - P + oh, ow - P - N);
        } else if (oh < P + N) {
            int ch = oh - P;
            if (ow < P)              v = L((i + 3) & 3, ch, N - P + ow);
            else if (ow < P + N)     v = L(face, ch, ow - P);
            else                     v = L(4 + ((i + 1) & 3), ch, ow - P - N);
        } else {
            int bh = oh - P - N;
            if (ow < P)              v = L(4 + ((i + 3) & 3), bh, N - P + ow);
            else if (ow < P + N)     v = L(8 + i, bh, ow - P);
            else {
                int bw = ow - P - N;
                if (bh == 0 && bw == 0)
                    v = 0.5f * L(8 + i, 0, N - 1) + 0.5f * L(8 + ((i + 3) & 3), N - 1, 0);
                else if (bh == 0)     v = L(8 + ((i + 3) & 3), N - 1, bw);
                else if (bw == 0)     v = L(8 + i, bh, N - 1);
                else                  v = 0.0f;
            }
        }
    } else {
        // ---- southern polar cap ----
        if (oh < P) {
            if (ow < P)              v = L(4 + i, N - P + oh, ow);
            else if (ow < P + N)     v = L(4 + i, N - P + oh, ow - P);
            else                     v = L(i, N - P + oh, N - P + (ow - P - N));
        } else if (oh < P + N) {
            int ch = oh - P;
            if (ow < P)              v = L(4 + ((i + 1) & 3), ch, N - P + ow);
            else if (ow < P + N)     v = L(face, ch, ow - P);
            else {
                int bw = ow - P - N;
                v = L(8 + ((i + 1) & 3), N - 1 - bw, ch);
            }
        } else {
            int bh = oh - P - N;
            if (ow < P)              v = L(8 + ((i + 1) & 3), N - P + ow, N - 1 - bh);
            else if (ow < P + N)     v = L(8 + ((i + 3) & 3), ow - P, N - 1 - bh);
            else {
                int bw = ow - P - N;
                v = L(8 + ((i + 3) & 3), N - 1 - bh, N - 1 - bw);
            }
        }
    }
    return v;
}

__global__ __launch_bounds__(256)
void healpix_pad4_kernel(const float* __restrict__ in, float* __restrict__ out) {
    int plane = blockIdx.y;                      // (b*12 + face)*C + c
    int idx   = blockIdx.x * blockDim.x + threadIdx.x;
    if (idx >= PLANE4) return;

    int oh = idx / ROW4;                          // output row
    int j  = idx - oh * ROW4;                     // float4 index within row

    int bc   = plane >> 5;                        // b*12 + face   (C=32)
    int face = bc >= 12 ? bc - 12 : bc;
    int i    = face & 3;
    int basePlane = plane - face * C;

    const float* __restrict__ cplane = in + (size_t)plane * PLANE_IN;

    float4 v;
    if (oh >= P && oh < P + N) {
        int ch = oh - P;
        const float* __restrict__ src = cplane + ch * N;
        if (j >= 1 && j < ROW4 - 1) {
            // output cols 4j..4j+3  ->  input cols 4j-2..4j+1 (8B aligned)
            float2 a = *reinterpret_cast<const float2*>(src + 4 * j - 2);
            float2 b = *reinterpret_cast<const float2*>(src + 4 * j);
            v = make_float4(a.x, a.y, b.x, b.y);
        } else if (j == 0) {
            v.x = gather(in, basePlane, face, i, oh, 0);
            v.y = gather(in, basePlane, face, i, oh, 1);
            float2 a = *reinterpret_cast<const float2*>(src);
            v.z = a.x; v.w = a.y;
        } else { // j == ROW4-1: cols 256,257 center; 258,259 halo
            float2 a = *reinterpret_cast<const float2*>(src + N - 2);
            v.x = a.x; v.y = a.y;
            v.z = gather(in, basePlane, face, i, oh, NP - 2);
            v.w = gather(in, basePlane, face, i, oh, NP - 1);
        }
    } else {
        int ow = 4 * j;
        v.x = gather(in, basePlane, face, i, oh, ow);
        v.y = gather(in, basePlane, face, i, oh, ow + 1);
        v.z = gather(in, basePlane, face, i, oh, ow + 2);
        v.w = gather(in, basePlane, face, i, oh, ow + 3);
    }

    *reinterpret_cast<float4*>(out + (size_t)plane * PLANE_OUT + (size_t)idx * 4) = v;
}

extern "C" void kernel_launch(void* const* d_in, const int* in_sizes, int n_in,
                              void* d_out, int out_size, void* d_ws, size_t ws_size,
                              hipStream_t stream) {
    const float* in = (const float*)d_in[0];
    float* out = (float*)d_out;
    int planes = out_size / PLANE_OUT;            // 2*12*32 = 768
    dim3 block(256);
    dim3 grid((PLANE4 + 255) / 256, planes);
    healpix_pad4_kernel<<<grid, block, 0, stream>>>(in, out);
}

// Round 4
// 78.289 us; speedup vs baseline: 1.8932x; 1.2122x over previous
//
#include <hip/hip_runtime.h>

// HEALPixPad: x (B=2, 12, C=32, 256, 256) f32 -> (B, 12, C, 260, 260) f32, P=2.
// Bulk/halo split: bulk blocks do a divergence-free aligned-float4 row copy
// (input row r -> output row r+2, cols 2..257, nontemporal stores); halo
// blocks fill the 2-wide edge strips using the round-1-verified gather.

constexpr int N  = 256;
constexpr int P  = 2;
constexpr int NP = N + 2 * P;        // 260
constexpr int C  = 32;
constexpr int PLANE_OUT = NP * NP;   // 67600
constexpr int PLANE_IN  = N * N;     // 65536
constexpr int BULK_BLOCKS = 64;      // 64 blocks * (4 rows x 64 float4) = 256 rows

typedef float f32x4 __attribute__((ext_vector_type(4)));

// Per-element gather with the full HEALPix neighbor mapping (round-1 verified).
__device__ __forceinline__ float gather(const float* __restrict__ in,
                                        int basePlane, int face, int i,
                                        int oh, int ow) {
    auto L = [&](int f, int sh, int sw) -> float {
        return in[(size_t)(basePlane + f * C) * PLANE_IN + sh * N + sw];
    };

    float v;
    if (face < 4) {
        // ---- northern polar cap ----
        if (oh < P) {
            if (ow < P)              v = L((i + 2) & 3, P - 1 - oh, P - 1 - ow);
            else if (ow < P + N)     v = L((i + 1) & 3, ow - P, P - 1 - oh);
            else                     v = L((i + 1) & 3, ow - P - N, P - 1 - oh);
        } else if (oh < P + N) {
            int ch = oh - P;
            if (ow < P)              v = L((i + 3) & 3, P - 1 - ow, ch);
            else if (ow < P + N)     v = L(face, ch, ow - P);
            else                     v = L(4 + ((i + 1) & 3), ch, ow - P - N);
        } else {
            int bh = oh - P - N;
            if (ow < P)              v = L((i + 3) & 3, bh, N - P + ow);
            else if (ow < P + N)     v = L(4 + i, bh, ow - P);
            else                     v = L(8 + i, bh, ow - P - N);
        }
    } else if (face < 8) {
        // ---- equatorial belt ----
        if (oh < P) {
            if (ow < P) {
                if (oh == P - 1 && ow == P - 1)
                    v = 0.5f * L(i, N - 1, 0) + 0.5f * L((i + 3) & 3, 0, N - 1);
                else if (oh == P - 1) v = L((i + 3) & 3, 0, N - P + ow);
                else if (ow == P - 1) v = L(i, N - P + oh, 0);
                else                  v = 0.0f;
            }
            else if (ow < P + N)     v = L(i, N - P + oh, ow - P);
            else                     v = L(i, N - P + oh, ow - P - N);
        } else if (oh < P + N) {
            int ch = oh - P;
            if (ow < P)              v = L((i + 3) & 3, ch, N - P + ow);
            else if (ow < P + N)     v = L(face, ch, ow - P);
            else                     v = L(4 + ((i + 1) & 3), ch, ow - P - N);
        } else {
            int bh = oh - P - N;
            if (ow < P)              v = L(4 + ((i + 3) & 3), bh, N - P + ow);
            else if (ow < P + N)     v = L(8 + i, bh, ow - P);
            else {
                int bw = ow - P - N;
                if (bh == 0 && bw == 0)
                    v = 0.5f * L(8 + i, 0, N - 1) + 0.5f * L(8 + ((i + 3) & 3), N - 1, 0);
                else if (bh == 0)     v = L(8 + ((i + 3) & 3), N - 1, bw);
                else if (bw == 0)     v = L(8 + i, bh, N - 1);
                else                  v = 0.0f;
            }
        }
    } else {
        // ---- southern polar cap ----
        if (oh < P) {
            if (ow < P)              v = L(4 + i, N - P + oh, ow);
            else if (ow < P + N)     v = L(4 + i, N - P + oh, ow - P);
            else                     v = L(i, N - P + oh, N - P + (ow - P - N));
        } else if (oh < P + N) {
            int ch = oh - P;
            if (ow < P)              v = L(4 + ((i + 1) & 3), ch, N - P + ow);
            else if (ow < P + N)     v = L(face, ch, ow - P);
            else {
                int bw = ow - P - N;
                v = L(8 + ((i + 1) & 3), N - 1 - bw, ch);
            }
        } else {
            int bh = oh - P - N;
            if (ow < P)              v = L(8 + ((i + 1) & 3), N - P + ow, N - 1 - bh);
            else if (ow < P + N)     v = L(8 + ((i + 3) & 3), ow - P, N - 1 - bh);
            else {
                int bw = ow - P - N;
                v = L(8 + ((i + 3) & 3), N - 1 - bh, N - 1 - bw);
            }
        }
    }
    return v;
}

__global__ __launch_bounds__(256)
void healpix_pad_kernel(const float* __restrict__ in, float* __restrict__ out) {
    const int plane = blockIdx.y;                 // (b*12 + face)*C + c
    const int x     = blockIdx.x;

    float* __restrict__ oplane = out + (size_t)plane * PLANE_OUT;

    if (x < BULK_BLOCKS) {
        // ---- divergence-free bulk copy: input row r -> output (r+2, cols 2..257)
        const int k   = threadIdx.x & 63;          // float4 index within row
        const int row = (x << 2) + (threadIdx.x >> 6);
        const float* __restrict__ src = in + (size_t)plane * PLANE_IN + row * N;
        f32x4 v = *reinterpret_cast<const f32x4*>(src + 4 * k);
        float* dst = oplane + (row + P) * NP + 4 * k + P;   // 8B-aligned
        __builtin_nontemporal_store(v, reinterpret_cast<f32x4*>(dst));
        return;
    }

    // ---- halo blocks: 4 blocks x 256 threads cover 772 tasks per plane
    const int t = (x - BULK_BLOCKS) * 256 + threadIdx.x;
    if (t >= 772) return;

    const int bc   = plane >> 5;                   // b*12 + face   (C=32)
    const int face = bc >= 12 ? bc - 12 : bc;
    const int i    = face & 3;
    const int basePlane = plane - face * C;

    if (t < 260) {
        // top rows 0,1 and bottom rows 258,259: one float4 each
        int tt  = t;
        int row = (tt < 130) ? (tt / 65) : (258 + (tt - 130) / 65);
        int j   = (tt < 130) ? (tt % 65) : ((tt - 130) % 65);
        int ow  = 4 * j;
        f32x4 v;
        v.x = gather(in, basePlane, face, i, row, ow);
        v.y = gather(in, basePlane, face, i, row, ow + 1);
        v.z = gather(in, basePlane, face, i, row, ow + 2);
        v.w = gather(in, basePlane, face, i, row, ow + 3);
        *reinterpret_cast<f32x4*>(oplane + row * NP + ow) = v;
    } else if (t < 516) {
        // left strip, interior rows: cols 0,1
        int ch = t - 260;
        int oh = ch + P;
        float2 v;
        v.x = gather(in, basePlane, face, i, oh, 0);
        v.y = gather(in, basePlane, face, i, oh, 1);
        *reinterpret_cast<float2*>(oplane + oh * NP) = v;
    } else {
        // right strip, interior rows: cols 258,259
        int ch = t - 516;
        int oh = ch + P;
        float2 v;
        v.x = gather(in, basePlane, face, i, oh, NP - 2);
        v.y = gather(in, basePlane, face, i, oh, NP - 1);
        *reinterpret_cast<float2*>(oplane + oh * NP + NP - 2) = v;
    }
}

extern "C" void kernel_launch(void* const* d_in, const int* in_sizes, int n_in,
                              void* d_out, int out_size, void* d_ws, size_t ws_size,
                              hipStream_t stream) {
    const float* in = (const float*)d_in[0];
    float* out = (float*)d_out;
    int planes = out_size / PLANE_OUT;             // 2*12*32 = 768
    dim3 block(256);
    dim3 grid(BULK_BLOCKS + 4, planes);
    healpix_pad_kernel<<<grid, block, 0, stream>>>(in, out);
}